// Round 10
// baseline (209.330 us; speedup 1.0000x reference)
//
#include <hip/hip_runtime.h>
#include <hip/hip_bf16.h>

#define NQ      10
#define NLAYERS 4
#define D_IN    784
#define BLOCK   64             // ONE wave per workgroup = one batch state (R10 experiment:
                               // 4-wave blocks stuck at ~1.7 blocks/CU resident (21% occ);
                               // single-wave WGs pack at finest granularity, barrier ~free)
// LOCKED: waves_per_eu(2,8). Raising the occupancy floor to >=4 waves/EU (launch_bounds(.,4),
// waves_per_eu(4,8), BLOCK=1024) makes the RA force 64 VGPRs and spill the 32-reg
// statevector to scratch: 760+ MB HBM write traffic, +120-190 us (R3/R5/R7).
// LOCKED: reductions use plain __shfl_xor only. R8's DPP reductions + Walsh butterfly +
// readlane diverged nondeterministically across graph replays (post-timing absmax 0.79).
// DPP stays confined to rot_gate's full-exec lane_xor<1,2> (stable since R4).

// Amplitude index i (10 bits): i = lane(6 bits, i[9:4]) * 16 + r(4 bits, i[3:0]).
// Qubit q sits at bit P = 9-q.  P>=4 -> lane qubit (lane bit P-4), P<4 -> register qubit.

template<int LB>
__device__ __forceinline__ float lane_xor(float v) {
    if constexpr (LB == 1) {        // quad_perm [1,0,3,2]
        return __int_as_float(__builtin_amdgcn_update_dpp(
            0, __float_as_int(v), 0xB1, 0xF, 0xF, false));
    } else if constexpr (LB == 2) { // quad_perm [2,3,0,1]
        return __int_as_float(__builtin_amdgcn_update_dpp(
            0, __float_as_int(v), 0x4E, 0xF, 0xF, false));
    } else {
        return __shfl_xor(v, LB, 64);
    }
}

// ---- generic complex 2x2 gate (Rot) on bit position P ----
template<int P>
__device__ __forceinline__ void rot_gate(float (&ax)[16], float (&ay)[16], int lane,
                                         float4 gA, float4 gB) {
    if constexpr (P >= 4) {
        const int lb = 1 << (P - 4);
        const bool hi = (lane & lb) != 0;
        const float gdx = hi ? gB.z : gA.x, gdy = hi ? gB.w : gA.y;   // diagonal
        const float gox = hi ? gB.x : gA.z, goy = hi ? gB.y : gA.w;   // off-diagonal
#pragma unroll
        for (int r = 0; r < 16; r++) {
            float ox = lane_xor<lb>(ax[r]);
            float oy = lane_xor<lb>(ay[r]);
            float vx = ax[r], vy = ay[r];
            ax[r] = gdx * vx - gdy * vy + gox * ox - goy * oy;
            ay[r] = gdx * vy + gdy * vx + gox * oy + goy * ox;
        }
    } else {
        const int m = 1 << P;
#pragma unroll
        for (int r = 0; r < 16; r++) {
            if (!(r & m)) {
                const int r1 = r | m;
                float x0 = ax[r], y0 = ay[r], x1 = ax[r1], y1 = ay[r1];
                ax[r]  = gA.x * x0 - gA.y * y0 + gA.z * x1 - gA.w * y1;
                ay[r]  = gA.x * y0 + gA.y * x0 + gA.z * y1 + gA.w * x1;
                ax[r1] = gB.x * x0 - gB.y * y0 + gB.z * x1 - gB.w * y1;
                ay[r1] = gB.x * y0 + gB.y * x0 + gB.z * y1 + gB.w * x1;
            }
        }
    }
}

// ---- rot<9> with the PREVIOUS layer's CNOT(ctrl=reg bit0, tgt=lane bit 32) fused in ----
__device__ __forceinline__ void rot9_fused(float (&ax)[16], float (&ay)[16], int lane,
                                           float4 gA, float4 gB) {
    const bool hi = (lane & 32) != 0;
    const float gdx = hi ? gB.z : gA.x, gdy = hi ? gB.w : gA.y;
    const float gox = hi ? gB.x : gA.z, goy = hi ? gB.y : gA.w;
#pragma unroll
    for (int r = 0; r < 16; r++) {
        float ox = __shfl_xor(ax[r], 32, 64);
        float oy = __shfl_xor(ay[r], 32, 64);
        float vx = ax[r], vy = ay[r];
        if (!(r & 1)) {
            ax[r] = gdx * vx - gdy * vy + gox * ox - goy * oy;
            ay[r] = gdx * vy + gdy * vx + gox * oy + goy * ox;
        } else {   // fused CNOT: own/partner roles swapped
            ax[r] = gdx * ox - gdy * oy + gox * vx - goy * vy;
            ay[r] = gdx * oy + gdy * ox + gox * vy + goy * vx;
        }
    }
}

// ---- CNOT: control bit PC, target bit PT (only the non-chain cases remain) ----
template<int PC, int PT>
__device__ __forceinline__ void cnot_gate(float (&ax)[16], float (&ay)[16], int lane) {
    if constexpr (PC >= 4 && PT < 4) {                // lane control, register target
        const int mt = 1 << PT;
        const bool ctl = (lane & (1 << (PC - 4))) != 0;
#pragma unroll
        for (int r = 0; r < 16; r++) {
            if (!(r & mt)) {
                const int r1 = r | mt;
                float x0 = ax[r], y0 = ay[r], x1 = ax[r1], y1 = ay[r1];
                ax[r]  = ctl ? x1 : x0;  ay[r]  = ctl ? y1 : y0;
                ax[r1] = ctl ? x0 : x1;  ay[r1] = ctl ? y0 : y1;
            }
        }
    } else if constexpr (PC < 4 && PT >= 4) {         // register control, lane target
        const int mc = 1 << PC, mt = 1 << (PT - 4);
#pragma unroll
        for (int r = 0; r < 16; r++) {
            if (r & mc) {
                ax[r] = __shfl_xor(ax[r], mt, 64);
                ay[r] = __shfl_xor(ay[r], mt, 64);
            }
        }
    } else {                                          // register-register: free rename
        const int mc = 1 << PC, mt = 1 << PT;
#pragma unroll
        for (int r = 0; r < 16; r++) {
            if ((r & mc) && !(r & mt)) {
                const int r1 = r | mt;
                float t;
                t = ax[r]; ax[r] = ax[r1]; ax[r1] = t;
                t = ay[r]; ay[r] = ay[r1]; ay[r1] = t;
            }
        }
    }
}

__global__ __launch_bounds__(BLOCK)
__attribute__((amdgpu_waves_per_eu(2, 8)))
void qnet_kernel(
    const float* __restrict__ x,
    const float* __restrict__ Wp,
    const float* __restrict__ bp,
    const float* __restrict__ qw,
    const float* __restrict__ Wo,
    const float* __restrict__ bo,
    float* __restrict__ out, int B)
{
    __shared__ __align__(16) float gates[NLAYERS * NQ * 8];  // per-wave Rot matrix table

    const int lane  = threadIdx.x;      // single wave per block
    const int state = blockIdx.x;

    // ---- Rot gate table (single wave: barrier is intra-wave, ~free) ----
    if (lane < NLAYERS * NQ) {
        float phi = qw[lane * 3 + 0];
        float th  = qw[lane * 3 + 1];
        float om  = qw[lane * 3 + 2];
        float s, c;   sincosf(0.5f * th, &s, &c);
        float sap, cap; sincosf(0.5f * (phi + om), &sap, &cap);
        float sam, cam; sincosf(0.5f * (phi - om), &sam, &cam);
        float* g = &gates[lane * 8];
        g[0] =  cap * c;  g[1] = -sap * c;   // u00
        g[2] = -cam * s;  g[3] = -sam * s;   // u01
        g[4] =  cam * s;  g[5] = -sam * s;   // u10
        g[6] =  cap * c;  g[7] =  sap * c;   // u11
    }
    __syncthreads();
    if (state >= B) return;

    // ---- projection: h = tanh(x[state] @ Wp^T + bp), one wave per state ----
    float acc[NQ];
#pragma unroll
    for (int q = 0; q < NQ; q++) acc[q] = 0.f;
    const float* xrow = x + (size_t)state * D_IN;
    for (int d = lane; d < D_IN; d += 64) {
        float xv = xrow[d];
#pragma unroll
        for (int q = 0; q < NQ; q++) acc[q] += xv * Wp[q * D_IN + d];
    }
#pragma unroll
    for (int q = 0; q < NQ; q++) {
#pragma unroll
        for (int o = 1; o < 64; o <<= 1) acc[q] += __shfl_xor(acc[q], o, 64);
    }
    // lane q (q<10) owns qubit q's RY coefficients
    float myc = 1.f, mys = 0.f;
    if (lane < NQ) {
        float h = tanhf(acc[lane] + bp[lane]);
        sincosf(0.5f * h, &mys, &myc);
    }

    // ---- statevector |0..0> in registers (SoA) ----
    float ax[16], ay[16];
#pragma unroll
    for (int r = 0; r < 16; r++) { ax[r] = 0.f; ay[r] = 0.f; }
    if (lane == 0) ax[0] = 1.f;

    // Pull-index for the composite lane-CNOT chain: src_lane = Gray(lane)
    const int bidx = (lane ^ (lane >> 1)) << 2;

    // ---- layer 0: RY fused into Rot (U = Rot * RY, wave-uniform) ----
    {
        const float* gl = &gates[0];
        float c, s;
#define FROTQ(Q) \
        c = __shfl(myc, Q, 64); s = __shfl(mys, Q, 64); \
        { float4 gA = *(const float4*)(gl + Q * 8); \
          float4 gB = *(const float4*)(gl + Q * 8 + 4); \
          float4 uA, uB; \
          uA.x = gA.x * c + gA.z * s;  uA.y = gA.y * c + gA.w * s; \
          uA.z = gA.z * c - gA.x * s;  uA.w = gA.w * c - gA.y * s; \
          uB.x = gB.x * c + gB.z * s;  uB.y = gB.y * c + gB.w * s; \
          uB.z = gB.z * c - gB.x * s;  uB.w = gB.w * c - gB.y * s; \
          rot_gate<9 - Q>(ax, ay, lane, uA, uB); }
        FROTQ(0) FROTQ(1) FROTQ(2) FROTQ(3) FROTQ(4)
        FROTQ(5) FROTQ(6) FROTQ(7) FROTQ(8) FROTQ(9)
#undef FROTQ
        // CNOT ring (9,8)..(5,4) as one lane permutation
#pragma unroll
        for (int r = 0; r < 16; r++) {
            ax[r] = __int_as_float(__builtin_amdgcn_ds_bpermute(bidx, __float_as_int(ax[r])));
            ay[r] = __int_as_float(__builtin_amdgcn_ds_bpermute(bidx, __float_as_int(ay[r])));
        }
        cnot_gate<4, 3>(ax, ay, lane);
        cnot_gate<3, 2>(ax, ay, lane);
        cnot_gate<2, 1>(ax, ay, lane);
        cnot_gate<1, 0>(ax, ay, lane);
        // cnot<0,9> fused into next layer's rot<9>
    }

    // ---- layers 1..3 (first gate consumes previous layer's trailing cnot<0,9>) ----
    for (int l = 1; l < NLAYERS; l++) {
        const float* gl = &gates[l * NQ * 8];
        {   float4 gA = *(const float4*)(gl);
            float4 gB = *(const float4*)(gl + 4);
            rot9_fused(ax, ay, lane, gA, gB); }
#define ROTQ(Q) { float4 gA = *(const float4*)(gl + Q * 8); \
                  float4 gB = *(const float4*)(gl + Q * 8 + 4); \
                  rot_gate<9 - Q>(ax, ay, lane, gA, gB); }
        ROTQ(1) ROTQ(2) ROTQ(3) ROTQ(4)
        ROTQ(5) ROTQ(6) ROTQ(7) ROTQ(8) ROTQ(9)
#undef ROTQ
#pragma unroll
        for (int r = 0; r < 16; r++) {
            ax[r] = __int_as_float(__builtin_amdgcn_ds_bpermute(bidx, __float_as_int(ax[r])));
            ay[r] = __int_as_float(__builtin_amdgcn_ds_bpermute(bidx, __float_as_int(ay[r])));
        }
        cnot_gate<4, 3>(ax, ay, lane);
        cnot_gate<3, 2>(ax, ay, lane);
        cnot_gate<2, 1>(ax, ay, lane);
        cnot_gate<1, 0>(ax, ay, lane);
    }
    // layer 3's trailing cnot<0,9> applied for real (measurement follows)
    cnot_gate<0, 9>(ax, ay, lane);

    // ---- measurement: Z expectation per qubit (plain shfl reductions only) ----
    float S = 0.f, zr3 = 0.f, zr2 = 0.f, zr1 = 0.f, zr0 = 0.f;
#pragma unroll
    for (int r = 0; r < 16; r++) {
        float pr = ax[r] * ax[r] + ay[r] * ay[r];
        S += pr;
        zr3 += (r & 8) ? -pr : pr;
        zr2 += (r & 4) ? -pr : pr;
        zr1 += (r & 2) ? -pr : pr;
        zr0 += (r & 1) ? -pr : pr;
    }
    float zq[NQ];
    zq[6] = zr3; zq[7] = zr2; zq[8] = zr1; zq[9] = zr0;       // register qubits
#pragma unroll
    for (int q = 0; q < 6; q++)                                // lane qubits: lane bit 5-q
        zq[q] = ((lane >> (5 - q)) & 1) ? -S : S;
#pragma unroll
    for (int q = 0; q < NQ; q++) {
#pragma unroll
        for (int o = 1; o < 64; o <<= 1) zq[q] += __shfl_xor(zq[q], o, 64);
    }

    // ---- output projection: out[state] = zq @ Wo^T + bo ----
    if (lane < NQ) {
        const float* wrow = Wo + lane * NQ;
        float o = bo[lane];
#pragma unroll
        for (int q = 0; q < NQ; q++) o += zq[q] * wrow[q];
        out[(size_t)state * NQ + lane] = o;
    }
}

extern "C" void kernel_launch(void* const* d_in, const int* in_sizes, int n_in,
                              void* d_out, int out_size, void* d_ws, size_t ws_size,
                              hipStream_t stream) {
    const float* x  = (const float*)d_in[0];
    const float* Wp = (const float*)d_in[1];
    const float* bp = (const float*)d_in[2];
    const float* qw = (const float*)d_in[3];
    const float* Wo = (const float*)d_in[4];
    const float* bo = (const float*)d_in[5];
    float* out = (float*)d_out;

    const int B = in_sizes[0] / D_IN;                    // 8192 states, one per wave/block
    hipLaunchKernelGGL(qnet_kernel, dim3(B), dim3(BLOCK), 0, stream,
                       x, Wp, bp, qw, Wo, bo, out, B);
}

// Round 11
// 171.580 us; speedup vs baseline: 1.2200x; 1.2200x over previous
//
#include <hip/hip_runtime.h>
#include <hip/hip_bf16.h>

#define NQ      10
#define NLAYERS 4
#define D_IN    784
#define BLOCK   64             // ONE wave per workgroup = one batch state (R10: bench-neutral
                               // vs 4-wave blocks; kept for minimal barrier + finest packing)
// LOCKED: waves_per_eu(2,8). Raising the occupancy floor to >=4 waves/EU (launch_bounds(.,4),
// waves_per_eu(4,8), BLOCK=1024) makes the RA force 64 VGPRs and spill the 32-reg
// statevector to scratch: 760+ MB HBM write traffic, +120-190 us (R3/R5/R7).
// LOCKED: reductions use plain __shfl_xor only. R8's DPP reductions + Walsh butterfly +
// readlane diverged nondeterministically across graph replays (post-timing absmax 0.79).
// DPP stays confined to rot_gate's full-exec lane_xor<1,2> (stable since R4).
// R11: amplitudes stored as ext_vector float2 (re,im) -> packed v_pk_fma_f32 gate math
// (complex mul = i*v swap folds into VOP3P op_sel/neg). ext_vector (not HIP float2 struct)
// keeps SROA happy; R3's struct-based float2 array spilled.

// Amplitude index i (10 bits): i = lane(6 bits, i[9:4]) * 16 + r(4 bits, i[3:0]).
// Qubit q sits at bit P = 9-q.  P>=4 -> lane qubit (lane bit P-4), P<4 -> register qubit.

typedef __attribute__((ext_vector_type(2))) float f2;

__device__ __forceinline__ f2 cswapneg(f2 v) {   // i * v = (-im, re)
    f2 r; r.x = -v.y; r.y = v.x; return r;
}

template<int LB>
__device__ __forceinline__ float lane_xor(float v) {
    if constexpr (LB == 1) {        // quad_perm [1,0,3,2]
        return __int_as_float(__builtin_amdgcn_update_dpp(
            0, __float_as_int(v), 0xB1, 0xF, 0xF, false));
    } else if constexpr (LB == 2) { // quad_perm [2,3,0,1]
        return __int_as_float(__builtin_amdgcn_update_dpp(
            0, __float_as_int(v), 0x4E, 0xF, 0xF, false));
    } else {
        return __shfl_xor(v, LB, 64);
    }
}

template<int LB>
__device__ __forceinline__ f2 lane_xor2(f2 v) {
    f2 r; r.x = lane_xor<LB>(v.x); r.y = lane_xor<LB>(v.y); return r;
}

// ---- generic complex 2x2 gate (Rot) on bit position P, packed math ----
template<int P>
__device__ __forceinline__ void rot_gate(f2 (&a)[16], int lane, float4 gA, float4 gB) {
    if constexpr (P >= 4) {
        const int lb = 1 << (P - 4);
        const bool hi = (lane & lb) != 0;
        const float gdx = hi ? gB.z : gA.x, gdy = hi ? gB.w : gA.y;   // diagonal
        const float gox = hi ? gB.x : gA.z, goy = hi ? gB.y : gA.w;   // off-diagonal
#pragma unroll
        for (int r = 0; r < 16; r++) {
            f2 o = lane_xor2<lb>(a[r]);
            f2 v = a[r];
            a[r] = gdx * v + gdy * cswapneg(v) + gox * o + goy * cswapneg(o);
        }
    } else {
        const int m = 1 << P;
#pragma unroll
        for (int r = 0; r < 16; r++) {
            if (!(r & m)) {
                const int r1 = r | m;
                f2 A0 = a[r], A1 = a[r1];
                f2 i0 = cswapneg(A0), i1 = cswapneg(A1);
                a[r]  = gA.x * A0 + gA.y * i0 + gA.z * A1 + gA.w * i1;
                a[r1] = gB.x * A0 + gB.y * i0 + gB.z * A1 + gB.w * i1;
            }
        }
    }
}

// ---- rot<9> with the PREVIOUS layer's CNOT(ctrl=reg bit0, tgt=lane bit 32) fused in ----
__device__ __forceinline__ void rot9_fused(f2 (&a)[16], int lane, float4 gA, float4 gB) {
    const bool hi = (lane & 32) != 0;
    const float gdx = hi ? gB.z : gA.x, gdy = hi ? gB.w : gA.y;
    const float gox = hi ? gB.x : gA.z, goy = hi ? gB.y : gA.w;
#pragma unroll
    for (int r = 0; r < 16; r++) {
        f2 o; o.x = __shfl_xor(a[r].x, 32, 64); o.y = __shfl_xor(a[r].y, 32, 64);
        f2 v = a[r];
        if (!(r & 1)) {
            a[r] = gdx * v + gdy * cswapneg(v) + gox * o + goy * cswapneg(o);
        } else {   // fused CNOT: own/partner roles swapped
            a[r] = gdx * o + gdy * cswapneg(o) + gox * v + goy * cswapneg(v);
        }
    }
}

// ---- CNOT: control bit PC, target bit PT (only the non-chain cases remain) ----
template<int PC, int PT>
__device__ __forceinline__ void cnot_gate(f2 (&a)[16], int lane) {
    if constexpr (PC >= 4 && PT < 4) {                // lane control, register target
        const int mt = 1 << PT;
        const bool ctl = (lane & (1 << (PC - 4))) != 0;
#pragma unroll
        for (int r = 0; r < 16; r++) {
            if (!(r & mt)) {
                const int r1 = r | mt;
                f2 A0 = a[r], A1 = a[r1];
                f2 n0, n1;
                n0.x = ctl ? A1.x : A0.x;  n0.y = ctl ? A1.y : A0.y;
                n1.x = ctl ? A0.x : A1.x;  n1.y = ctl ? A0.y : A1.y;
                a[r] = n0; a[r1] = n1;
            }
        }
    } else if constexpr (PC < 4 && PT >= 4) {         // register control, lane target
        const int mc = 1 << PC, mt = 1 << (PT - 4);
#pragma unroll
        for (int r = 0; r < 16; r++) {
            if (r & mc) {
                a[r].x = __shfl_xor(a[r].x, mt, 64);
                a[r].y = __shfl_xor(a[r].y, mt, 64);
            }
        }
    } else {                                          // register-register: free rename
        const int mc = 1 << PC, mt = 1 << PT;
#pragma unroll
        for (int r = 0; r < 16; r++) {
            if ((r & mc) && !(r & mt)) {
                const int r1 = r | mt;
                f2 t = a[r]; a[r] = a[r1]; a[r1] = t;
            }
        }
    }
}

__global__ __launch_bounds__(BLOCK)
__attribute__((amdgpu_waves_per_eu(2, 8)))
void qnet_kernel(
    const float* __restrict__ x,
    const float* __restrict__ Wp,
    const float* __restrict__ bp,
    const float* __restrict__ qw,
    const float* __restrict__ Wo,
    const float* __restrict__ bo,
    float* __restrict__ out, int B)
{
    __shared__ __align__(16) float gates[NLAYERS * NQ * 8];  // per-wave Rot matrix table

    const int lane  = threadIdx.x;      // single wave per block
    const int state = blockIdx.x;

    // ---- Rot gate table (single wave: barrier is intra-wave, ~free) ----
    if (lane < NLAYERS * NQ) {
        float phi = qw[lane * 3 + 0];
        float th  = qw[lane * 3 + 1];
        float om  = qw[lane * 3 + 2];
        float s, c;   sincosf(0.5f * th, &s, &c);
        float sap, cap; sincosf(0.5f * (phi + om), &sap, &cap);
        float sam, cam; sincosf(0.5f * (phi - om), &sam, &cam);
        float* g = &gates[lane * 8];
        g[0] =  cap * c;  g[1] = -sap * c;   // u00
        g[2] = -cam * s;  g[3] = -sam * s;   // u01
        g[4] =  cam * s;  g[5] = -sam * s;   // u10
        g[6] =  cap * c;  g[7] =  sap * c;   // u11
    }
    __syncthreads();
    if (state >= B) return;

    // ---- projection: h = tanh(x[state] @ Wp^T + bp), one wave per state ----
    float acc[NQ];
#pragma unroll
    for (int q = 0; q < NQ; q++) acc[q] = 0.f;
    const float* xrow = x + (size_t)state * D_IN;
    for (int d = lane; d < D_IN; d += 64) {
        float xv = xrow[d];
#pragma unroll
        for (int q = 0; q < NQ; q++) acc[q] += xv * Wp[q * D_IN + d];
    }
#pragma unroll
    for (int q = 0; q < NQ; q++) {
#pragma unroll
        for (int o = 1; o < 64; o <<= 1) acc[q] += __shfl_xor(acc[q], o, 64);
    }
    // lane q (q<10) owns qubit q's RY coefficients
    float myc = 1.f, mys = 0.f;
    if (lane < NQ) {
        float h = tanhf(acc[lane] + bp[lane]);
        sincosf(0.5f * h, &mys, &myc);
    }

    // ---- statevector |0..0> in registers, packed (re,im) per VGPR pair ----
    f2 a[16];
#pragma unroll
    for (int r = 0; r < 16; r++) { a[r].x = 0.f; a[r].y = 0.f; }
    if (lane == 0) a[0].x = 1.f;

    // Pull-index for the composite lane-CNOT chain: src_lane = Gray(lane)
    const int bidx = (lane ^ (lane >> 1)) << 2;

    // ---- layer 0: RY fused into Rot (U = Rot * RY, wave-uniform) ----
    {
        const float* gl = &gates[0];
        float c, s;
#define FROTQ(Q) \
        c = __shfl(myc, Q, 64); s = __shfl(mys, Q, 64); \
        { float4 gA = *(const float4*)(gl + Q * 8); \
          float4 gB = *(const float4*)(gl + Q * 8 + 4); \
          float4 uA, uB; \
          uA.x = gA.x * c + gA.z * s;  uA.y = gA.y * c + gA.w * s; \
          uA.z = gA.z * c - gA.x * s;  uA.w = gA.w * c - gA.y * s; \
          uB.x = gB.x * c + gB.z * s;  uB.y = gB.y * c + gB.w * s; \
          uB.z = gB.z * c - gB.x * s;  uB.w = gB.w * c - gB.y * s; \
          rot_gate<9 - Q>(a, lane, uA, uB); }
        FROTQ(0) FROTQ(1) FROTQ(2) FROTQ(3) FROTQ(4)
        FROTQ(5) FROTQ(6) FROTQ(7) FROTQ(8) FROTQ(9)
#undef FROTQ
        // CNOT ring (9,8)..(5,4) as one lane permutation
#pragma unroll
        for (int r = 0; r < 16; r++) {
            a[r].x = __int_as_float(__builtin_amdgcn_ds_bpermute(bidx, __float_as_int(a[r].x)));
            a[r].y = __int_as_float(__builtin_amdgcn_ds_bpermute(bidx, __float_as_int(a[r].y)));
        }
        cnot_gate<4, 3>(a, lane);
        cnot_gate<3, 2>(a, lane);
        cnot_gate<2, 1>(a, lane);
        cnot_gate<1, 0>(a, lane);
        // cnot<0,9> fused into next layer's rot<9>
    }

    // ---- layers 1..3 (first gate consumes previous layer's trailing cnot<0,9>) ----
    for (int l = 1; l < NLAYERS; l++) {
        const float* gl = &gates[l * NQ * 8];
        {   float4 gA = *(const float4*)(gl);
            float4 gB = *(const float4*)(gl + 4);
            rot9_fused(a, lane, gA, gB); }
#define ROTQ(Q) { float4 gA = *(const float4*)(gl + Q * 8); \
                  float4 gB = *(const float4*)(gl + Q * 8 + 4); \
                  rot_gate<9 - Q>(a, lane, gA, gB); }
        ROTQ(1) ROTQ(2) ROTQ(3) ROTQ(4)
        ROTQ(5) ROTQ(6) ROTQ(7) ROTQ(8) ROTQ(9)
#undef ROTQ
#pragma unroll
        for (int r = 0; r < 16; r++) {
            a[r].x = __int_as_float(__builtin_amdgcn_ds_bpermute(bidx, __float_as_int(a[r].x)));
            a[r].y = __int_as_float(__builtin_amdgcn_ds_bpermute(bidx, __float_as_int(a[r].y)));
        }
        cnot_gate<4, 3>(a, lane);
        cnot_gate<3, 2>(a, lane);
        cnot_gate<2, 1>(a, lane);
        cnot_gate<1, 0>(a, lane);
    }
    // layer 3's trailing cnot<0,9> applied for real (measurement follows)
    cnot_gate<0, 9>(a, lane);

    // ---- measurement: Z expectation per qubit (plain shfl reductions only) ----
    float S = 0.f, zr3 = 0.f, zr2 = 0.f, zr1 = 0.f, zr0 = 0.f;
#pragma unroll
    for (int r = 0; r < 16; r++) {
        float pr = a[r].x * a[r].x + a[r].y * a[r].y;
        S += pr;
        zr3 += (r & 8) ? -pr : pr;
        zr2 += (r & 4) ? -pr : pr;
        zr1 += (r & 2) ? -pr : pr;
        zr0 += (r & 1) ? -pr : pr;
    }
    float zq[NQ];
    zq[6] = zr3; zq[7] = zr2; zq[8] = zr1; zq[9] = zr0;       // register qubits
#pragma unroll
    for (int q = 0; q < 6; q++)                                // lane qubits: lane bit 5-q
        zq[q] = ((lane >> (5 - q)) & 1) ? -S : S;
#pragma unroll
    for (int q = 0; q < NQ; q++) {
#pragma unroll
        for (int o = 1; o < 64; o <<= 1) zq[q] += __shfl_xor(zq[q], o, 64);
    }

    // ---- output projection: out[state] = zq @ Wo^T + bo ----
    if (lane < NQ) {
        const float* wrow = Wo + lane * NQ;
        float o = bo[lane];
#pragma unroll
        for (int q = 0; q < NQ; q++) o += zq[q] * wrow[q];
        out[(size_t)state * NQ + lane] = o;
    }
}

extern "C" void kernel_launch(void* const* d_in, const int* in_sizes, int n_in,
                              void* d_out, int out_size, void* d_ws, size_t ws_size,
                              hipStream_t stream) {
    const float* x  = (const float*)d_in[0];
    const float* Wp = (const float*)d_in[1];
    const float* bp = (const float*)d_in[2];
    const float* qw = (const float*)d_in[3];
    const float* Wo = (const float*)d_in[4];
    const float* bo = (const float*)d_in[5];
    float* out = (float*)d_out;

    const int B = in_sizes[0] / D_IN;                    // 8192 states, one per wave/block
    hipLaunchKernelGGL(qnet_kernel, dim3(B), dim3(BLOCK), 0, stream,
                       x, Wp, bp, qw, Wo, bo, out, B);
}

// Round 12
// 165.977 us; speedup vs baseline: 1.2612x; 1.0338x over previous
//
#include <hip/hip_runtime.h>
#include <hip/hip_bf16.h>

#define NQ      10
#define NLAYERS 4
#define D_IN    784
#define BLOCK   64             // ONE wave per workgroup; R12: each wave simulates TWO states
                               // (interleaved for ILP — occupancy is stuck at ~2 waves/SIMD
                               // across R9/R10 experiments, so latency must be hidden in-wave)
// LOCKED: waves_per_eu(2,8). Raising the occupancy floor to >=4 waves/EU (launch_bounds(.,4),
// waves_per_eu(4,8), BLOCK=1024) makes the RA force 64 VGPRs and spill the statevector:
// 760+ MB HBM write traffic, +120-190 us (R3/R5/R7). Watch WRITE_SIZE (~0.5 MB when clean).
// LOCKED: reductions use plain __shfl_xor only. R8's DPP reductions + Walsh butterfly +
// readlane diverged nondeterministically across graph replays (post-timing absmax 0.79).
// DPP stays confined to rot_gate's full-exec lane_xor<1,2> (stable since R4).
// R11: ext_vector float2 (re,im) amplitudes -> packed v_pk_* math. 209 -> 171 us.

// Amplitude index i (10 bits): i = lane(6 bits, i[9:4]) * 16 + r(4 bits, i[3:0]).
// Qubit q sits at bit P = 9-q.  P>=4 -> lane qubit (lane bit P-4), P<4 -> register qubit.

typedef __attribute__((ext_vector_type(2))) float f2;

__device__ __forceinline__ f2 cswapneg(f2 v) {   // i * v = (-im, re)
    f2 r; r.x = -v.y; r.y = v.x; return r;
}

template<int LB>
__device__ __forceinline__ float lane_xor(float v) {
    if constexpr (LB == 1) {        // quad_perm [1,0,3,2]
        return __int_as_float(__builtin_amdgcn_update_dpp(
            0, __float_as_int(v), 0xB1, 0xF, 0xF, false));
    } else if constexpr (LB == 2) { // quad_perm [2,3,0,1]
        return __int_as_float(__builtin_amdgcn_update_dpp(
            0, __float_as_int(v), 0x4E, 0xF, 0xF, false));
    } else {
        return __shfl_xor(v, LB, 64);
    }
}

template<int LB>
__device__ __forceinline__ f2 lane_xor2(f2 v) {
    f2 r; r.x = lane_xor<LB>(v.x); r.y = lane_xor<LB>(v.y); return r;
}

// ---- generic complex 2x2 gate (Rot) on bit position P, two states interleaved ----
template<int P>
__device__ __forceinline__ void rot_gate2(f2 (&a)[16], f2 (&b)[16], int lane,
                                          float4 gA, float4 gB) {
    if constexpr (P >= 4) {
        const int lb = 1 << (P - 4);
        const bool hi = (lane & lb) != 0;
        const float gdx = hi ? gB.z : gA.x, gdy = hi ? gB.w : gA.y;   // diagonal
        const float gox = hi ? gB.x : gA.z, goy = hi ? gB.y : gA.w;   // off-diagonal
#pragma unroll
        for (int r = 0; r < 16; r++) {
            f2 oa = lane_xor2<lb>(a[r]);
            f2 ob = lane_xor2<lb>(b[r]);
            f2 va = a[r], vb = b[r];
            a[r] = gdx * va + gdy * cswapneg(va) + gox * oa + goy * cswapneg(oa);
            b[r] = gdx * vb + gdy * cswapneg(vb) + gox * ob + goy * cswapneg(ob);
        }
    } else {
        const int m = 1 << P;
#pragma unroll
        for (int r = 0; r < 16; r++) {
            if (!(r & m)) {
                const int r1 = r | m;
                f2 A0 = a[r], A1 = a[r1];
                f2 B0 = b[r], B1 = b[r1];
                f2 ia0 = cswapneg(A0), ia1 = cswapneg(A1);
                f2 ib0 = cswapneg(B0), ib1 = cswapneg(B1);
                a[r]  = gA.x * A0 + gA.y * ia0 + gA.z * A1 + gA.w * ia1;
                b[r]  = gA.x * B0 + gA.y * ib0 + gA.z * B1 + gA.w * ib1;
                a[r1] = gB.x * A0 + gB.y * ia0 + gB.z * A1 + gB.w * ia1;
                b[r1] = gB.x * B0 + gB.y * ib0 + gB.z * B1 + gB.w * ib1;
            }
        }
    }
}

// ---- layer-0 variant: per-state matrices (RY fused, angles differ per state) ----
template<int P>
__device__ __forceinline__ void rot_gate2ab(f2 (&a)[16], f2 (&b)[16], int lane,
                                            float4 aAm, float4 aBm,
                                            float4 bAm, float4 bBm) {
    if constexpr (P >= 4) {
        const int lb = 1 << (P - 4);
        const bool hi = (lane & lb) != 0;
        const float adx = hi ? aBm.z : aAm.x, ady = hi ? aBm.w : aAm.y;
        const float aox = hi ? aBm.x : aAm.z, aoy = hi ? aBm.y : aAm.w;
        const float bdx = hi ? bBm.z : bAm.x, bdy = hi ? bBm.w : bAm.y;
        const float box = hi ? bBm.x : bAm.z, boy = hi ? bBm.y : bAm.w;
#pragma unroll
        for (int r = 0; r < 16; r++) {
            f2 oa = lane_xor2<lb>(a[r]);
            f2 ob = lane_xor2<lb>(b[r]);
            f2 va = a[r], vb = b[r];
            a[r] = adx * va + ady * cswapneg(va) + aox * oa + aoy * cswapneg(oa);
            b[r] = bdx * vb + bdy * cswapneg(vb) + box * ob + boy * cswapneg(ob);
        }
    } else {
        const int m = 1 << P;
#pragma unroll
        for (int r = 0; r < 16; r++) {
            if (!(r & m)) {
                const int r1 = r | m;
                f2 A0 = a[r], A1 = a[r1];
                f2 B0 = b[r], B1 = b[r1];
                f2 ia0 = cswapneg(A0), ia1 = cswapneg(A1);
                f2 ib0 = cswapneg(B0), ib1 = cswapneg(B1);
                a[r]  = aAm.x * A0 + aAm.y * ia0 + aAm.z * A1 + aAm.w * ia1;
                b[r]  = bAm.x * B0 + bAm.y * ib0 + bAm.z * B1 + bAm.w * ib1;
                a[r1] = aBm.x * A0 + aBm.y * ia0 + aBm.z * A1 + aBm.w * ia1;
                b[r1] = bBm.x * B0 + bBm.y * ib0 + bBm.z * B1 + bBm.w * ib1;
            }
        }
    }
}

// ---- rot<9> with the PREVIOUS layer's CNOT(ctrl=reg bit0, tgt=lane bit 32) fused in ----
__device__ __forceinline__ void rot9_fused2(f2 (&a)[16], f2 (&b)[16], int lane,
                                            float4 gA, float4 gB) {
    const bool hi = (lane & 32) != 0;
    const float gdx = hi ? gB.z : gA.x, gdy = hi ? gB.w : gA.y;
    const float gox = hi ? gB.x : gA.z, goy = hi ? gB.y : gA.w;
#pragma unroll
    for (int r = 0; r < 16; r++) {
        f2 oa; oa.x = __shfl_xor(a[r].x, 32, 64); oa.y = __shfl_xor(a[r].y, 32, 64);
        f2 ob; ob.x = __shfl_xor(b[r].x, 32, 64); ob.y = __shfl_xor(b[r].y, 32, 64);
        f2 va = a[r], vb = b[r];
        if (!(r & 1)) {
            a[r] = gdx * va + gdy * cswapneg(va) + gox * oa + goy * cswapneg(oa);
            b[r] = gdx * vb + gdy * cswapneg(vb) + gox * ob + goy * cswapneg(ob);
        } else {   // fused CNOT: own/partner roles swapped
            a[r] = gdx * oa + gdy * cswapneg(oa) + gox * va + goy * cswapneg(va);
            b[r] = gdx * ob + gdy * cswapneg(ob) + gox * vb + goy * cswapneg(vb);
        }
    }
}

// ---- CNOT on both states: control bit PC, target bit PT ----
template<int PC, int PT>
__device__ __forceinline__ void cnot_gate2(f2 (&a)[16], f2 (&b)[16], int lane) {
    if constexpr (PC >= 4 && PT < 4) {                // lane control, register target
        const int mt = 1 << PT;
        const bool ctl = (lane & (1 << (PC - 4))) != 0;
#pragma unroll
        for (int r = 0; r < 16; r++) {
            if (!(r & mt)) {
                const int r1 = r | mt;
                f2 A0 = a[r], A1 = a[r1], B0 = b[r], B1 = b[r1];
                f2 na0, na1, nb0, nb1;
                na0.x = ctl ? A1.x : A0.x;  na0.y = ctl ? A1.y : A0.y;
                na1.x = ctl ? A0.x : A1.x;  na1.y = ctl ? A0.y : A1.y;
                nb0.x = ctl ? B1.x : B0.x;  nb0.y = ctl ? B1.y : B0.y;
                nb1.x = ctl ? B0.x : B1.x;  nb1.y = ctl ? B0.y : B1.y;
                a[r] = na0; a[r1] = na1; b[r] = nb0; b[r1] = nb1;
            }
        }
    } else if constexpr (PC < 4 && PT >= 4) {         // register control, lane target
        const int mc = 1 << PC, mt = 1 << (PT - 4);
#pragma unroll
        for (int r = 0; r < 16; r++) {
            if (r & mc) {
                a[r].x = __shfl_xor(a[r].x, mt, 64);
                a[r].y = __shfl_xor(a[r].y, mt, 64);
                b[r].x = __shfl_xor(b[r].x, mt, 64);
                b[r].y = __shfl_xor(b[r].y, mt, 64);
            }
        }
    } else {                                          // register-register: free rename
        const int mc = 1 << PC, mt = 1 << PT;
#pragma unroll
        for (int r = 0; r < 16; r++) {
            if ((r & mc) && !(r & mt)) {
                const int r1 = r | mt;
                f2 t = a[r]; a[r] = a[r1]; a[r1] = t;
                f2 u = b[r]; b[r] = b[r1]; b[r1] = u;
            }
        }
    }
}

__global__ __launch_bounds__(BLOCK)
__attribute__((amdgpu_waves_per_eu(2, 8)))
void qnet_kernel(
    const float* __restrict__ x,
    const float* __restrict__ Wp,
    const float* __restrict__ bp,
    const float* __restrict__ qw,
    const float* __restrict__ Wo,
    const float* __restrict__ bo,
    float* __restrict__ out, int B)
{
    __shared__ __align__(16) float gates[NLAYERS * NQ * 8];  // per-wave Rot matrix table

    const int lane = threadIdx.x;       // single wave per block
    const int s0   = blockIdx.x * 2;    // this wave's two states
    const int s1   = s0 + 1;

    // ---- Rot gate table (single wave: barrier is intra-wave, ~free) ----
    if (lane < NLAYERS * NQ) {
        float phi = qw[lane * 3 + 0];
        float th  = qw[lane * 3 + 1];
        float om  = qw[lane * 3 + 2];
        float s, c;   sincosf(0.5f * th, &s, &c);
        float sap, cap; sincosf(0.5f * (phi + om), &sap, &cap);
        float sam, cam; sincosf(0.5f * (phi - om), &sam, &cam);
        float* g = &gates[lane * 8];
        g[0] =  cap * c;  g[1] = -sap * c;   // u00
        g[2] = -cam * s;  g[3] = -sam * s;   // u01
        g[4] =  cam * s;  g[5] = -sam * s;   // u10
        g[6] =  cap * c;  g[7] =  sap * c;   // u11
    }
    __syncthreads();
    if (s0 >= B) return;

    // ---- projection for both states (Wp value shared) ----
    float acc0[NQ], acc1[NQ];
#pragma unroll
    for (int q = 0; q < NQ; q++) { acc0[q] = 0.f; acc1[q] = 0.f; }
    const float* xr0 = x + (size_t)s0 * D_IN;
    const float* xr1 = x + (size_t)s1 * D_IN;
    for (int d = lane; d < D_IN; d += 64) {
        float x0 = xr0[d], x1 = xr1[d];
#pragma unroll
        for (int q = 0; q < NQ; q++) {
            float w = Wp[q * D_IN + d];
            acc0[q] += x0 * w;
            acc1[q] += x1 * w;
        }
    }
#pragma unroll
    for (int q = 0; q < NQ; q++) {
#pragma unroll
        for (int o = 1; o < 64; o <<= 1) {
            acc0[q] += __shfl_xor(acc0[q], o, 64);
            acc1[q] += __shfl_xor(acc1[q], o, 64);
        }
    }
    float myc0 = 1.f, mys0 = 0.f, myc1 = 1.f, mys1 = 0.f;
    if (lane < NQ) {
        float h0 = tanhf(acc0[lane] + bp[lane]);
        float h1 = tanhf(acc1[lane] + bp[lane]);
        sincosf(0.5f * h0, &mys0, &myc0);
        sincosf(0.5f * h1, &mys1, &myc1);
    }

    // ---- statevectors |0..0> in registers, packed (re,im) ----
    f2 a[16], b[16];
#pragma unroll
    for (int r = 0; r < 16; r++) { a[r].x = 0.f; a[r].y = 0.f; b[r].x = 0.f; b[r].y = 0.f; }
    if (lane == 0) { a[0].x = 1.f; b[0].x = 1.f; }

    // Pull-index for the composite lane-CNOT chain: src_lane = Gray(lane)
    const int bidx = (lane ^ (lane >> 1)) << 2;

    // ---- layer 0: RY fused into Rot (per-state matrices) ----
    {
        const float* gl = &gates[0];
        float c0, ss0, c1, ss1;
#define FROTQ(Q) \
        c0 = __shfl(myc0, Q, 64); ss0 = __shfl(mys0, Q, 64); \
        c1 = __shfl(myc1, Q, 64); ss1 = __shfl(mys1, Q, 64); \
        { float4 gA = *(const float4*)(gl + Q * 8); \
          float4 gB = *(const float4*)(gl + Q * 8 + 4); \
          float4 aAm, aBm, bAm, bBm; \
          aAm.x = gA.x * c0 + gA.z * ss0;  aAm.y = gA.y * c0 + gA.w * ss0; \
          aAm.z = gA.z * c0 - gA.x * ss0;  aAm.w = gA.w * c0 - gA.y * ss0; \
          aBm.x = gB.x * c0 + gB.z * ss0;  aBm.y = gB.y * c0 + gB.w * ss0; \
          aBm.z = gB.z * c0 - gB.x * ss0;  aBm.w = gB.w * c0 - gB.y * ss0; \
          bAm.x = gA.x * c1 + gA.z * ss1;  bAm.y = gA.y * c1 + gA.w * ss1; \
          bAm.z = gA.z * c1 - gA.x * ss1;  bAm.w = gA.w * c1 - gA.y * ss1; \
          bBm.x = gB.x * c1 + gB.z * ss1;  bBm.y = gB.y * c1 + gB.w * ss1; \
          bBm.z = gB.z * c1 - gB.x * ss1;  bBm.w = gB.w * c1 - gB.y * ss1; \
          rot_gate2ab<9 - Q>(a, b, lane, aAm, aBm, bAm, bBm); }
        FROTQ(0) FROTQ(1) FROTQ(2) FROTQ(3) FROTQ(4)
        FROTQ(5) FROTQ(6) FROTQ(7) FROTQ(8) FROTQ(9)
#undef FROTQ
        // CNOT ring (9,8)..(5,4) as one lane permutation, both states
#pragma unroll
        for (int r = 0; r < 16; r++) {
            a[r].x = __int_as_float(__builtin_amdgcn_ds_bpermute(bidx, __float_as_int(a[r].x)));
            a[r].y = __int_as_float(__builtin_amdgcn_ds_bpermute(bidx, __float_as_int(a[r].y)));
            b[r].x = __int_as_float(__builtin_amdgcn_ds_bpermute(bidx, __float_as_int(b[r].x)));
            b[r].y = __int_as_float(__builtin_amdgcn_ds_bpermute(bidx, __float_as_int(b[r].y)));
        }
        cnot_gate2<4, 3>(a, b, lane);
        cnot_gate2<3, 2>(a, b, lane);
        cnot_gate2<2, 1>(a, b, lane);
        cnot_gate2<1, 0>(a, b, lane);
        // cnot<0,9> fused into next layer's rot<9>
    }

    // ---- layers 1..3 (first gate consumes previous layer's trailing cnot<0,9>) ----
    for (int l = 1; l < NLAYERS; l++) {
        const float* gl = &gates[l * NQ * 8];
        {   float4 gA = *(const float4*)(gl);
            float4 gB = *(const float4*)(gl + 4);
            rot9_fused2(a, b, lane, gA, gB); }
#define ROTQ(Q) { float4 gA = *(const float4*)(gl + Q * 8); \
                  float4 gB = *(const float4*)(gl + Q * 8 + 4); \
                  rot_gate2<9 - Q>(a, b, lane, gA, gB); }
        ROTQ(1) ROTQ(2) ROTQ(3) ROTQ(4)
        ROTQ(5) ROTQ(6) ROTQ(7) ROTQ(8) ROTQ(9)
#undef ROTQ
#pragma unroll
        for (int r = 0; r < 16; r++) {
            a[r].x = __int_as_float(__builtin_amdgcn_ds_bpermute(bidx, __float_as_int(a[r].x)));
            a[r].y = __int_as_float(__builtin_amdgcn_ds_bpermute(bidx, __float_as_int(a[r].y)));
            b[r].x = __int_as_float(__builtin_amdgcn_ds_bpermute(bidx, __float_as_int(b[r].x)));
            b[r].y = __int_as_float(__builtin_amdgcn_ds_bpermute(bidx, __float_as_int(b[r].y)));
        }
        cnot_gate2<4, 3>(a, b, lane);
        cnot_gate2<3, 2>(a, b, lane);
        cnot_gate2<2, 1>(a, b, lane);
        cnot_gate2<1, 0>(a, b, lane);
    }
    // layer 3's trailing cnot<0,9> applied for real (measurement follows)
    cnot_gate2<0, 9>(a, b, lane);

    // ---- measurement: Z expectation per qubit, both states ----
    float S0 = 0.f, za3 = 0.f, za2 = 0.f, za1 = 0.f, za0 = 0.f;
    float S1 = 0.f, zb3 = 0.f, zb2 = 0.f, zb1 = 0.f, zb0 = 0.f;
#pragma unroll
    for (int r = 0; r < 16; r++) {
        float pa = a[r].x * a[r].x + a[r].y * a[r].y;
        float pb = b[r].x * b[r].x + b[r].y * b[r].y;
        S0 += pa;  S1 += pb;
        za3 += (r & 8) ? -pa : pa;   zb3 += (r & 8) ? -pb : pb;
        za2 += (r & 4) ? -pa : pa;   zb2 += (r & 4) ? -pb : pb;
        za1 += (r & 2) ? -pa : pa;   zb1 += (r & 2) ? -pb : pb;
        za0 += (r & 1) ? -pa : pa;   zb0 += (r & 1) ? -pb : pb;
    }
    float zqa[NQ], zqb[NQ];
    zqa[6] = za3; zqa[7] = za2; zqa[8] = za1; zqa[9] = za0;
    zqb[6] = zb3; zqb[7] = zb2; zqb[8] = zb1; zqb[9] = zb0;
#pragma unroll
    for (int q = 0; q < 6; q++) {                      // lane qubits: lane bit 5-q
        zqa[q] = ((lane >> (5 - q)) & 1) ? -S0 : S0;
        zqb[q] = ((lane >> (5 - q)) & 1) ? -S1 : S1;
    }
#pragma unroll
    for (int q = 0; q < NQ; q++) {
#pragma unroll
        for (int o = 1; o < 64; o <<= 1) {
            zqa[q] += __shfl_xor(zqa[q], o, 64);
            zqb[q] += __shfl_xor(zqb[q], o, 64);
        }
    }

    // ---- output projection: out = zq @ Wo^T + bo, both states ----
    if (lane < NQ) {
        const float* wrow = Wo + lane * NQ;
        float o0 = bo[lane], o1 = o0;
#pragma unroll
        for (int q = 0; q < NQ; q++) {
            float w = wrow[q];
            o0 += zqa[q] * w;
            o1 += zqb[q] * w;
        }
        out[(size_t)s0 * NQ + lane] = o0;
        out[(size_t)s1 * NQ + lane] = o1;
    }
}

extern "C" void kernel_launch(void* const* d_in, const int* in_sizes, int n_in,
                              void* d_out, int out_size, void* d_ws, size_t ws_size,
                              hipStream_t stream) {
    const float* x  = (const float*)d_in[0];
    const float* Wp = (const float*)d_in[1];
    const float* bp = (const float*)d_in[2];
    const float* qw = (const float*)d_in[3];
    const float* Wo = (const float*)d_in[4];
    const float* bo = (const float*)d_in[5];
    float* out = (float*)d_out;

    const int B = in_sizes[0] / D_IN;                    // 8192 states, two per wave/block
    const int blocks = (B + 1) / 2;
    hipLaunchKernelGGL(qnet_kernel, dim3(blocks), dim3(BLOCK), 0, stream,
                       x, Wp, bp, qw, Wo, bo, out, B);
}